// Round 10
// baseline (14.950 us; speedup 1.0000x reference)
//
#include <hip/hip_runtime.h>
#include <hip/hip_bf16.h>

// Block-diagonal attention, x:[8,16,671,64] f32, blocks [0,128),[128,256),
// [256,384),[543,671); gap rows [384,543) -> 0.
// One WG (256 thr = 4 waves) per (head,block); wave owns 32 q-rows (nq=2
// subtiles) so K/V LDS fragments are read ONCE per wave and reused across
// both q-subtiles: per-WG LDS read volume drops 304->176 KB vs the 8-wave
// shape. XOR-chunk-swizzled unpadded LDS (conflict-free), swapped QK^T,
// in-lane softmax, in-register P via cvt_pk + permlane swaps, balanced
// gap-zero, PV ne-outer with early per-ne stores.

typedef __attribute__((ext_vector_type(8))) short short8;   // 8 x bf16
typedef __attribute__((ext_vector_type(4))) float floatx4;  // MFMA acc
typedef __attribute__((ext_vector_type(4))) int intx4;
typedef __attribute__((ext_vector_type(2))) unsigned int uint2v;

__device__ __forceinline__ int cvt_pk_bf16(float lo, float hi) {
    int r;
    asm("v_cvt_pk_bf16_f32 %0, %1, %2" : "=v"(r) : "v"(lo), "v"(hi));
    return r;
}

// [X,Y] -> (r0, r1), r0 = [X.g0, X.g2, Y.g0, Y.g2], r1 = [X.g1, X.g3, Y.g1, Y.g3]
// (g = 16-lane group) — exactly the PV B-frag words.
__device__ __forceinline__ uint2v dswap(unsigned a, unsigned b) {
    uint2v t = __builtin_amdgcn_permlane32_swap(a, b, false, false);
    return __builtin_amdgcn_permlane16_swap(t[0], t[1], false, false);
}

__global__ __launch_bounds__(256, 2)
void blockattn_kernel(const float* __restrict__ x, float* __restrict__ out)
{
    __shared__ __align__(16) unsigned short xb[128 * 64]; // swizzled [t][k]
    __shared__ __align__(16) unsigned short xt[64 * 128]; // swizzled [e][t]

    const int wg  = blockIdx.x;
    const int h   = wg >> 2;
    const int blk = wg & 3;
    const int rowbase = (blk < 3) ? (blk << 7) : 543;
    const float* xp = x   + ((size_t)h * 671 + rowbase) * 64;
    float*       op = out + ((size_t)h * 671 + rowbase) * 64;

    const int tid  = threadIdx.x;
    const int lane = tid & 63;
    const int wid  = tid >> 6;          // 0..3

    // ---- stage: each thread owns 4 full 16B chunks (4x2 float4 loads)
    float4 f[4][2];
    #pragma unroll
    for (int it = 0; it < 4; ++it) {
        const int i = tid + it * 256;   // chunk id 0..1023 (8 floats each)
        f[it][0] = *reinterpret_cast<const float4*>(xp + i * 8);
        f[it][1] = *reinterpret_cast<const float4*>(xp + i * 8 + 4);
    }

    // ---- gap zero, BALANCED: rows [384+blk*40, +40) (39 for blk3)
    {
        const int start = 384 + blk * 40;
        const int cnt16 = ((blk < 3) ? 40 : 39) * 16;   // float4 count
        float* gp = out + ((size_t)h * 671 + start) * 64;
        #pragma unroll
        for (int it = 0; it < 3; ++it) {
            int i4 = tid + it * 256;
            if (i4 < cnt16)
                *reinterpret_cast<float4*>(gp + i4 * 4) = make_float4(0.f, 0.f, 0.f, 0.f);
        }
    }

    // ---- convert f32->bf16, one b128 per chunk, swizzled (conflict-free)
    #pragma unroll
    for (int it = 0; it < 4; ++it) {
        const int i = tid + it * 256;
        const int r = i >> 3, c = i & 7;
        union { intx4 i4; short8 s; } u;
        u.i4 = (intx4){cvt_pk_bf16(f[it][0].x, f[it][0].y),
                       cvt_pk_bf16(f[it][0].z, f[it][0].w),
                       cvt_pk_bf16(f[it][1].x, f[it][1].y),
                       cvt_pk_bf16(f[it][1].z, f[it][1].w)};
        *reinterpret_cast<short8*>(&xb[r * 64 + ((c ^ (r & 7)) << 3)]) = u.s;
    }
    __syncthreads();

    const int l15 = lane & 15;
    const int lhi = lane >> 4;

    // ---- S^T = K · Q : 32 q-rows (nq=2), K-frags read once, reused
    short8 bq[2][2];
    #pragma unroll
    for (int nq = 0; nq < 2; ++nq)
        #pragma unroll
        for (int kk = 0; kk < 2; ++kk)
            bq[nq][kk] = *reinterpret_cast<const short8*>(
                &xb[(wid * 32 + nq * 16 + l15) * 64 + ((((kk << 2) + lhi) ^ (l15 & 7)) << 3)]);

    floatx4 sT[8][2];
    #pragma unroll
    for (int mt = 0; mt < 8; ++mt)
        #pragma unroll
        for (int nq = 0; nq < 2; ++nq)
            sT[mt][nq] = (floatx4){0.f, 0.f, 0.f, 0.f};

    #pragma unroll
    for (int mt = 0; mt < 8; ++mt) {
        short8 ak[2];
        #pragma unroll
        for (int kk = 0; kk < 2; ++kk)
            ak[kk] = *reinterpret_cast<const short8*>(
                &xb[(mt * 16 + l15) * 64 + ((((kk << 2) + lhi) ^ (l15 & 7)) << 3)]);
        #pragma unroll
        for (int nq = 0; nq < 2; ++nq)
            #pragma unroll
            for (int kk = 0; kk < 2; ++kk)
                sT[mt][nq] = __builtin_amdgcn_mfma_f32_16x16x32_bf16(ak[kk], bq[nq][kk], sT[mt][nq], 0, 0, 0);
    }

    // ---- build xt = V^T via LDS->LDS transpose (overlaps MFMA above)
    #pragma unroll
    for (int it2 = 0; it2 < 4; ++it2) {
        const int c = wid + it2 * 4;             // t-chunk 0..15
        short8 w;
        #pragma unroll
        for (int j = 0; j < 8; ++j)
            w[j] = (short)xb[(c * 8 + j) * 64 + (((lane >> 3) ^ j) << 3) + (lane & 7)];
        *reinterpret_cast<short8*>(&xt[lane * 128 + ((c ^ (lane & 15)) << 3)]) = w;
    }

    // ---- softmax per nq: tree max (v_max3), in-lane exp2, 2 shuffles
    // Lane (lhi,l15): sT[mt][nq][j] = S[q=wid*32+nq*16+l15][t=16mt+4*lhi+j]
    const float C2 = 0.125f * 1.44269504088896340736f;  // scale * log2(e)
    int   pk[8][2][2];
    float rinv[2];
    #pragma unroll
    for (int nq = 0; nq < 2; ++nq) {
        float pm[8];
        #pragma unroll
        for (int mt = 0; mt < 8; ++mt)
            pm[mt] = fmaxf(fmaxf(sT[mt][nq][0], sT[mt][nq][1]),
                           fmaxf(sT[mt][nq][2], sT[mt][nq][3]));
        float m0 = fmaxf(fmaxf(pm[0], pm[1]), fmaxf(pm[2], pm[3]));
        float m1 = fmaxf(fmaxf(pm[4], pm[5]), fmaxf(pm[6], pm[7]));
        float mx = fmaxf(m0, m1);
        mx = fmaxf(mx, __shfl_xor(mx, 16, 64));
        mx = fmaxf(mx, __shfl_xor(mx, 32, 64));
        float sum = 0.f;
        #pragma unroll
        for (int mt = 0; mt < 8; ++mt) {
            float e0 = exp2f((sT[mt][nq][0] - mx) * C2);
            float e1 = exp2f((sT[mt][nq][1] - mx) * C2);
            float e2 = exp2f((sT[mt][nq][2] - mx) * C2);
            float e3 = exp2f((sT[mt][nq][3] - mx) * C2);
            sum += (e0 + e1) + (e2 + e3);
            pk[mt][nq][0] = cvt_pk_bf16(e0, e1);
            pk[mt][nq][1] = cvt_pk_bf16(e2, e3);
        }
        sum += __shfl_xor(sum, 16, 64);
        sum += __shfl_xor(sum, 32, 64);
        rinv[nq] = 1.f / sum;
    }
    __syncthreads();   // xt complete before PV reads

    // ---- precompute all PV B-frags (pure VALU; sT dead by now)
    short8 pb[4][2];
    #pragma unroll
    for (int kk = 0; kk < 4; ++kk)
        #pragma unroll
        for (int nq = 0; nq < 2; ++nq) {
            uint2v rA = dswap((unsigned)pk[2 * kk][nq][0], (unsigned)pk[2 * kk + 1][nq][0]);
            uint2v rB = dswap((unsigned)pk[2 * kk][nq][1], (unsigned)pk[2 * kk + 1][nq][1]);
            union { intx4 i; short8 s; } u;
            u.i = (intx4){(int)rA[0], (int)rB[0], (int)rA[1], (int)rB[1]};
            pb[kk][nq] = u.s;
        }

    // ---- O^T = V^T · P^T : ne-outer, av read once per (ne,kk) reused for
    // both nq; per-ne stores issue early and drain under remaining MFMAs
    #pragma unroll
    for (int ne = 0; ne < 4; ++ne) {
        floatx4 o0 = (floatx4){0.f, 0.f, 0.f, 0.f};
        floatx4 o1 = (floatx4){0.f, 0.f, 0.f, 0.f};
        #pragma unroll
        for (int kk = 0; kk < 4; ++kk) {
            short8 av = *reinterpret_cast<const short8*>(
                &xt[(ne * 16 + l15) * 128 + ((((kk << 2) + lhi) ^ l15) << 3)]);
            o0 = __builtin_amdgcn_mfma_f32_16x16x32_bf16(av, pb[kk][0], o0, 0, 0, 0);
            o1 = __builtin_amdgcn_mfma_f32_16x16x32_bf16(av, pb[kk][1], o1, 0, 0, 0);
        }
        const int q0 = wid * 32 + l15;
        float4 v0 = make_float4(o0[0] * rinv[0], o0[1] * rinv[0],
                                o0[2] * rinv[0], o0[3] * rinv[0]);
        *reinterpret_cast<float4*>(&op[q0 * 64 + ne * 16 + lhi * 4]) = v0;
        float4 v1 = make_float4(o1[0] * rinv[1], o1[1] * rinv[1],
                                o1[2] * rinv[1], o1[3] * rinv[1]);
        *reinterpret_cast<float4*>(&op[(q0 + 16) * 64 + ne * 16 + lhi * 4]) = v1;
    }
}

extern "C" void kernel_launch(void* const* d_in, const int* in_sizes, int n_in,
                              void* d_out, int out_size, void* d_ws, size_t ws_size,
                              hipStream_t stream)
{
    const float* x = (const float*)d_in[0];
    float* out     = (float*)d_out;
    hipLaunchKernelGGL(blockattn_kernel, dim3(512), dim3(256), 0, stream, x, out);
}

// Round 11
// 14.088 us; speedup vs baseline: 1.0612x; 1.0612x over previous
//
#include <hip/hip_runtime.h>
#include <hip/hip_bf16.h>

// Block-diagonal attention, x:[8,16,671,64] f32, blocks [0,128),[128,256),
// [256,384),[543,671); gap rows [384,543) -> 0.
// One WG (512 thr = 8 waves) per (head,block); wave owns 16 q-rows.
// Round-9 structure (XOR-chunk-swizzled unpadded LDS, swapped QK^T,
// in-lane softmax, in-register P via cvt_pk + permlane swaps, balanced
// gap-zero) with stores spread into compute-idle memory slots:
//   (a) PV is ne-outer with per-ne normalize+store (3/4 of O stores drain
//       under remaining PV MFMAs instead of after them)
//   (b) gap-zero stores moved into the QK^T phase (memory pipe idle there)

typedef __attribute__((ext_vector_type(8))) short short8;   // 8 x bf16
typedef __attribute__((ext_vector_type(4))) float floatx4;  // MFMA acc
typedef __attribute__((ext_vector_type(4))) int intx4;
typedef __attribute__((ext_vector_type(2))) unsigned int uint2v;

__device__ __forceinline__ int cvt_pk_bf16(float lo, float hi) {
    int r;
    asm("v_cvt_pk_bf16_f32 %0, %1, %2" : "=v"(r) : "v"(lo), "v"(hi));
    return r;
}

// [X,Y] -> (r0, r1), r0 = [X.g0, X.g2, Y.g0, Y.g2], r1 = [X.g1, X.g3, Y.g1, Y.g3]
// (g = 16-lane group) — exactly the PV B-frag words.
__device__ __forceinline__ uint2v dswap(unsigned a, unsigned b) {
    uint2v t = __builtin_amdgcn_permlane32_swap(a, b, false, false);
    return __builtin_amdgcn_permlane16_swap(t[0], t[1], false, false);
}

__global__ __launch_bounds__(512, 4)
void blockattn_kernel(const float* __restrict__ x, float* __restrict__ out)
{
    __shared__ __align__(16) unsigned short xb[128 * 64]; // swizzled [t][k]
    __shared__ __align__(16) unsigned short xt[64 * 128]; // swizzled [e][t]

    const int wg  = blockIdx.x;
    const int h   = wg >> 2;
    const int blk = wg & 3;
    const int rowbase = (blk < 3) ? (blk << 7) : 543;
    const float* xp = x   + ((size_t)h * 671 + rowbase) * 64;
    float*       op = out + ((size_t)h * 671 + rowbase) * 64;

    const int tid  = threadIdx.x;
    const int lane = tid & 63;
    const int wid  = tid >> 6;          // 0..7

    // ---- stage: each thread owns 2 full 16B chunks (2x2 float4 loads)
    float4 f[2][2];
    #pragma unroll
    for (int it = 0; it < 2; ++it) {
        const int i = tid + it * 512;   // chunk id 0..1023 (8 floats each)
        f[it][0] = *reinterpret_cast<const float4*>(xp + i * 8);
        f[it][1] = *reinterpret_cast<const float4*>(xp + i * 8 + 4);
    }

    // ---- convert f32->bf16, one b128 per chunk, swizzled (conflict-free)
    #pragma unroll
    for (int it = 0; it < 2; ++it) {
        const int i = tid + it * 512;
        const int r = i >> 3, c = i & 7;
        union { intx4 i4; short8 s; } u;
        u.i4 = (intx4){cvt_pk_bf16(f[it][0].x, f[it][0].y),
                       cvt_pk_bf16(f[it][0].z, f[it][0].w),
                       cvt_pk_bf16(f[it][1].x, f[it][1].y),
                       cvt_pk_bf16(f[it][1].z, f[it][1].w)};
        *reinterpret_cast<short8*>(&xb[r * 64 + ((c ^ (r & 7)) << 3)]) = u.s;
    }
    __syncthreads();

    // ---- gap zero, BALANCED + placed in the compute phase (memory idle):
    // this WG zeroes rows [384+blk*40, +40) (39 for blk3)
    {
        const int start = 384 + blk * 40;
        const int cnt16 = ((blk < 3) ? 40 : 39) * 16;   // float4 count
        float* gp = out + ((size_t)h * 671 + start) * 64;
        #pragma unroll
        for (int it = 0; it < 2; ++it) {
            int i4 = tid + it * 512;
            if (i4 < cnt16)
                *reinterpret_cast<float4*>(gp + i4 * 4) = make_float4(0.f, 0.f, 0.f, 0.f);
        }
    }

    const int l15 = lane & 15;
    const int lhi = lane >> 4;

    // ---- S^T = K · Q : this wave's 16 q-rows, C: row=t-part, col=q-part
    short8 bq[2];
    #pragma unroll
    for (int kk = 0; kk < 2; ++kk)
        bq[kk] = *reinterpret_cast<const short8*>(
            &xb[(wid * 16 + l15) * 64 + ((((kk << 2) + lhi) ^ (l15 & 7)) << 3)]);

    floatx4 sT[8];
    #pragma unroll
    for (int mt = 0; mt < 8; ++mt)
        sT[mt] = (floatx4){0.f, 0.f, 0.f, 0.f};

    #pragma unroll
    for (int mt = 0; mt < 8; ++mt) {
        short8 ak[2];
        #pragma unroll
        for (int kk = 0; kk < 2; ++kk)
            ak[kk] = *reinterpret_cast<const short8*>(
                &xb[(mt * 16 + l15) * 64 + ((((kk << 2) + lhi) ^ (l15 & 7)) << 3)]);
        #pragma unroll
        for (int kk = 0; kk < 2; ++kk)
            sT[mt] = __builtin_amdgcn_mfma_f32_16x16x32_bf16(ak[kk], bq[kk], sT[mt], 0, 0, 0);
    }

    // ---- build xt = V^T via LDS->LDS transpose (overlaps MFMA above)
    #pragma unroll
    for (int it2 = 0; it2 < 2; ++it2) {
        const int c = wid + it2 * 8;             // t-chunk 0..15
        short8 w;
        #pragma unroll
        for (int j = 0; j < 8; ++j)
            w[j] = (short)xb[(c * 8 + j) * 64 + (((lane >> 3) ^ j) << 3) + (lane & 7)];
        *reinterpret_cast<short8*>(&xt[lane * 128 + ((c ^ (lane & 15)) << 3)]) = w;
    }

    // ---- softmax: tree max (v_max3), in-lane exp2, 2 shuffles; pack P bf16
    // Lane (lhi,l15): sT[mt][j] = S[q=wid*16+l15][t=16mt+4*lhi+j]
    const float C2 = 0.125f * 1.44269504088896340736f;  // scale * log2(e)
    int   pk[8][2];
    float rinv;
    {
        float pm[8];
        #pragma unroll
        for (int mt = 0; mt < 8; ++mt)
            pm[mt] = fmaxf(fmaxf(sT[mt][0], sT[mt][1]), fmaxf(sT[mt][2], sT[mt][3]));
        float m0 = fmaxf(fmaxf(pm[0], pm[1]), fmaxf(pm[2], pm[3]));
        float m1 = fmaxf(fmaxf(pm[4], pm[5]), fmaxf(pm[6], pm[7]));
        float mx = fmaxf(m0, m1);
        mx = fmaxf(mx, __shfl_xor(mx, 16, 64));
        mx = fmaxf(mx, __shfl_xor(mx, 32, 64));
        float sum = 0.f;
        #pragma unroll
        for (int mt = 0; mt < 8; ++mt) {
            float e0 = exp2f((sT[mt][0] - mx) * C2);
            float e1 = exp2f((sT[mt][1] - mx) * C2);
            float e2 = exp2f((sT[mt][2] - mx) * C2);
            float e3 = exp2f((sT[mt][3] - mx) * C2);
            sum += (e0 + e1) + (e2 + e3);
            pk[mt][0] = cvt_pk_bf16(e0, e1);
            pk[mt][1] = cvt_pk_bf16(e2, e3);
        }
        sum += __shfl_xor(sum, 16, 64);
        sum += __shfl_xor(sum, 32, 64);
        rinv = 1.f / sum;
    }
    __syncthreads();   // xt complete before PV reads

    // ---- precompute PV B-frags (pure VALU; sT dead by now)
    short8 pb[4];
    #pragma unroll
    for (int kk = 0; kk < 4; ++kk) {
        uint2v rA = dswap((unsigned)pk[2 * kk][0], (unsigned)pk[2 * kk + 1][0]);
        uint2v rB = dswap((unsigned)pk[2 * kk][1], (unsigned)pk[2 * kk + 1][1]);
        union { intx4 i; short8 s; } u;
        u.i = (intx4){(int)rA[0], (int)rB[0], (int)rA[1], (int)rB[1]};
        pb[kk] = u.s;
    }

    // ---- O^T = V^T · P^T : ne-outer; each ne's store issues right after its
    // 4 MFMAs, draining under the remaining PV work
    const int q = wid * 16 + l15;
    #pragma unroll
    for (int ne = 0; ne < 4; ++ne) {
        floatx4 o = (floatx4){0.f, 0.f, 0.f, 0.f};
        #pragma unroll
        for (int kk = 0; kk < 4; ++kk) {
            short8 av = *reinterpret_cast<const short8*>(
                &xt[(ne * 16 + l15) * 128 + ((((kk << 2) + lhi) ^ l15) << 3)]);
            o = __builtin_amdgcn_mfma_f32_16x16x32_bf16(av, pb[kk], o, 0, 0, 0);
        }
        float4 v = make_float4(o[0] * rinv, o[1] * rinv,
                               o[2] * rinv, o[3] * rinv);
        *reinterpret_cast<float4*>(&op[q * 64 + ne * 16 + lhi * 4]) = v;
    }
}

extern "C" void kernel_launch(void* const* d_in, const int* in_sizes, int n_in,
                              void* d_out, int out_size, void* d_ws, size_t ws_size,
                              hipStream_t stream)
{
    const float* x = (const float*)d_in[0];
    float* out     = (float*)d_out;
    hipLaunchKernelGGL(blockattn_kernel, dim3(512), dim3(512), 0, stream, x, out);
}

// Round 12
// 13.914 us; speedup vs baseline: 1.0745x; 1.0125x over previous
//
#include <hip/hip_runtime.h>
#include <hip/hip_bf16.h>

// Block-diagonal attention, x:[8,16,671,64] f32, blocks [0,128),[128,256),
// [256,384),[543,671); gap rows [384,543) -> 0.
// One WG (512 thr = 8 waves) per (head,block); wave owns 16 q-rows.
// ONE-BARRIER variant of the round-9/11 structure: V^T (xt) is built during
// the staging phase from a second, column-coalesced global read pass (like
// r2's pass B) instead of a post-QK LDS->LDS transpose. Both xb and xt are
// complete at the single __syncthreads(); afterwards every wave runs its
// QK -> softmax -> PV -> store chain independently (no lockstep, stores
// spread naturally). Swizzled conflict-free LDS, in-lane softmax,
// in-register P via cvt_pk + permlane swaps, balanced gap-zero.

typedef __attribute__((ext_vector_type(8))) short short8;   // 8 x bf16
typedef __attribute__((ext_vector_type(4))) float floatx4;  // MFMA acc
typedef __attribute__((ext_vector_type(4))) int intx4;
typedef __attribute__((ext_vector_type(2))) unsigned int uint2v;

__device__ __forceinline__ int cvt_pk_bf16(float lo, float hi) {
    int r;
    asm("v_cvt_pk_bf16_f32 %0, %1, %2" : "=v"(r) : "v"(lo), "v"(hi));
    return r;
}

// [X,Y] -> (r0, r1), r0 = [X.g0, X.g2, Y.g0, Y.g2], r1 = [X.g1, X.g3, Y.g1, Y.g3]
// (g = 16-lane group) — exactly the PV B-frag words.
__device__ __forceinline__ uint2v dswap(unsigned a, unsigned b) {
    uint2v t = __builtin_amdgcn_permlane32_swap(a, b, false, false);
    return __builtin_amdgcn_permlane16_swap(t[0], t[1], false, false);
}

__global__ __launch_bounds__(512, 4)
void blockattn_kernel(const float* __restrict__ x, float* __restrict__ out)
{
    __shared__ __align__(16) unsigned short xb[128 * 64]; // swizzled [t][k]
    __shared__ __align__(16) unsigned short xt[64 * 128]; // swizzled [e][t]

    const int wg  = blockIdx.x;
    const int h   = wg >> 2;
    const int blk = wg & 3;
    const int rowbase = (blk < 3) ? (blk << 7) : 543;
    const float* xp = x   + ((size_t)h * 671 + rowbase) * 64;
    float*       op = out + ((size_t)h * 671 + rowbase) * 64;

    const int tid  = threadIdx.x;
    const int lane = tid & 63;
    const int wid  = tid >> 6;          // 0..7

    // ---- pass A: row chunks for xb (each thread owns 2 full 16B chunks)
    float4 f[2][2];
    #pragma unroll
    for (int it = 0; it < 2; ++it) {
        const int i = tid + it * 512;   // chunk id 0..1023 (8 floats each)
        f[it][0] = *reinterpret_cast<const float4*>(xp + i * 8);
        f[it][1] = *reinterpret_cast<const float4*>(xp + i * 8 + 4);
    }

    // ---- pass B: column gather for xt (e = lane, t-chunks c = wid + 8*it2)
    // for fixed (c,j) the 64 lanes read consecutive dwords: fully coalesced
    float vbf[16];
    #pragma unroll
    for (int it2 = 0; it2 < 2; ++it2) {
        const int c = wid + it2 * 8;
        #pragma unroll
        for (int j = 0; j < 8; ++j)
            vbf[it2 * 8 + j] = xp[(c * 8 + j) * 64 + lane];
    }

    // ---- convert + LDS writes, both swizzled conflict-free
    #pragma unroll
    for (int it = 0; it < 2; ++it) {
        const int i = tid + it * 512;
        const int r = i >> 3, c = i & 7;
        union { intx4 i4; short8 s; } u;
        u.i4 = (intx4){cvt_pk_bf16(f[it][0].x, f[it][0].y),
                       cvt_pk_bf16(f[it][0].z, f[it][0].w),
                       cvt_pk_bf16(f[it][1].x, f[it][1].y),
                       cvt_pk_bf16(f[it][1].z, f[it][1].w)};
        *reinterpret_cast<short8*>(&xb[r * 64 + ((c ^ (r & 7)) << 3)]) = u.s;
    }
    #pragma unroll
    for (int it2 = 0; it2 < 2; ++it2) {
        const int c = wid + it2 * 8;
        union { intx4 i4; short8 s; } u;
        u.i4 = (intx4){cvt_pk_bf16(vbf[it2 * 8 + 0], vbf[it2 * 8 + 1]),
                       cvt_pk_bf16(vbf[it2 * 8 + 2], vbf[it2 * 8 + 3]),
                       cvt_pk_bf16(vbf[it2 * 8 + 4], vbf[it2 * 8 + 5]),
                       cvt_pk_bf16(vbf[it2 * 8 + 6], vbf[it2 * 8 + 7])};
        *reinterpret_cast<short8*>(&xt[lane * 128 + ((c ^ (lane & 15)) << 3)]) = u.s;
    }
    __syncthreads();    // the ONLY barrier: xb and xt both ready

    // ---- gap zero, BALANCED, in the compute phase (memory pipe idle here)
    {
        const int start = 384 + blk * 40;
        const int cnt16 = ((blk < 3) ? 40 : 39) * 16;   // float4 count
        float* gp = out + ((size_t)h * 671 + start) * 64;
        #pragma unroll
        for (int it = 0; it < 2; ++it) {
            int i4 = tid + it * 512;
            if (i4 < cnt16)
                *reinterpret_cast<float4*>(gp + i4 * 4) = make_float4(0.f, 0.f, 0.f, 0.f);
        }
    }

    const int l15 = lane & 15;
    const int lhi = lane >> 4;

    // ---- S^T = K · Q : this wave's 16 q-rows, C: row=t-part, col=q-part
    short8 bq[2];
    #pragma unroll
    for (int kk = 0; kk < 2; ++kk)
        bq[kk] = *reinterpret_cast<const short8*>(
            &xb[(wid * 16 + l15) * 64 + ((((kk << 2) + lhi) ^ (l15 & 7)) << 3)]);

    floatx4 sT[8];
    #pragma unroll
    for (int mt = 0; mt < 8; ++mt)
        sT[mt] = (floatx4){0.f, 0.f, 0.f, 0.f};

    #pragma unroll
    for (int mt = 0; mt < 8; ++mt) {
        short8 ak[2];
        #pragma unroll
        for (int kk = 0; kk < 2; ++kk)
            ak[kk] = *reinterpret_cast<const short8*>(
                &xb[(mt * 16 + l15) * 64 + ((((kk << 2) + lhi) ^ (l15 & 7)) << 3)]);
        #pragma unroll
        for (int kk = 0; kk < 2; ++kk)
            sT[mt] = __builtin_amdgcn_mfma_f32_16x16x32_bf16(ak[kk], bq[kk], sT[mt], 0, 0, 0);
    }

    // ---- softmax: tree max (v_max3), in-lane exp2, 2 shuffles; pack P bf16
    // Lane (lhi,l15): sT[mt][j] = S[q=wid*16+l15][t=16mt+4*lhi+j]
    const float C2 = 0.125f * 1.44269504088896340736f;  // scale * log2(e)
    int   pk[8][2];
    float rinv;
    {
        float pm[8];
        #pragma unroll
        for (int mt = 0; mt < 8; ++mt)
            pm[mt] = fmaxf(fmaxf(sT[mt][0], sT[mt][1]), fmaxf(sT[mt][2], sT[mt][3]));
        float m0 = fmaxf(fmaxf(pm[0], pm[1]), fmaxf(pm[2], pm[3]));
        float m1 = fmaxf(fmaxf(pm[4], pm[5]), fmaxf(pm[6], pm[7]));
        float mx = fmaxf(m0, m1);
        mx = fmaxf(mx, __shfl_xor(mx, 16, 64));
        mx = fmaxf(mx, __shfl_xor(mx, 32, 64));
        float sum = 0.f;
        #pragma unroll
        for (int mt = 0; mt < 8; ++mt) {
            float e0 = exp2f((sT[mt][0] - mx) * C2);
            float e1 = exp2f((sT[mt][1] - mx) * C2);
            float e2 = exp2f((sT[mt][2] - mx) * C2);
            float e3 = exp2f((sT[mt][3] - mx) * C2);
            sum += (e0 + e1) + (e2 + e3);
            pk[mt][0] = cvt_pk_bf16(e0, e1);
            pk[mt][1] = cvt_pk_bf16(e2, e3);
        }
        sum += __shfl_xor(sum, 16, 64);
        sum += __shfl_xor(sum, 32, 64);
        rinv = 1.f / sum;
    }
    // no second barrier: xt was written before the staging barrier

    // ---- precompute PV B-frags (pure VALU; sT dead by now)
    short8 pb[4];
    #pragma unroll
    for (int kk = 0; kk < 4; ++kk) {
        uint2v rA = dswap((unsigned)pk[2 * kk][0], (unsigned)pk[2 * kk + 1][0]);
        uint2v rB = dswap((unsigned)pk[2 * kk][1], (unsigned)pk[2 * kk + 1][1]);
        union { intx4 i; short8 s; } u;
        u.i = (intx4){(int)rA[0], (int)rB[0], (int)rA[1], (int)rB[1]};
        pb[kk] = u.s;
    }

    // ---- O^T = V^T · P^T : ne-outer; each ne's store issues right after its
    // 4 MFMAs, draining under the remaining PV work
    const int q = wid * 16 + l15;
    #pragma unroll
    for (int ne = 0; ne < 4; ++ne) {
        floatx4 o = (floatx4){0.f, 0.f, 0.f, 0.f};
        #pragma unroll
        for (int kk = 0; kk < 4; ++kk) {
            short8 av = *reinterpret_cast<const short8*>(
                &xt[(ne * 16 + l15) * 128 + ((((kk << 2) + lhi) ^ l15) << 3)]);
            o = __builtin_amdgcn_mfma_f32_16x16x32_bf16(av, pb[kk], o, 0, 0, 0);
        }
        float4 v = make_float4(o[0] * rinv, o[1] * rinv,
                               o[2] * rinv, o[3] * rinv);
        *reinterpret_cast<float4*>(&op[q * 64 + ne * 16 + lhi * 4]) = v;
    }
}

extern "C" void kernel_launch(void* const* d_in, const int* in_sizes, int n_in,
                              void* d_out, int out_size, void* d_ws, size_t ws_size,
                              hipStream_t stream)
{
    const float* x = (const float*)d_in[0];
    float* out     = (float*)d_out;
    hipLaunchKernelGGL(blockattn_kernel, dim3(512), dim3(512), 0, stream, x, out);
}